// Round 17
// baseline (491.474 us; speedup 1.0000x reference)
//
#include <hip/hip_runtime.h>

#define N_NODES  100000
#define N_GRAPHS 1000
#define N_EDGES  3200000
#define HDIM     64
#define NROWS    (N_NODES + 1)                         // +1 sentinel zero row

#define BUCK_LOG 8
#define BUCK_SZ  256
#define NBUCK    ((N_NODES + BUCK_SZ - 1) / BUCK_SZ)   // 391
#define CAP      16384                                 // slack slots per bucket
#define BIN_T    256
#define BIN_E    16
#define BIN_CHUNK (BIN_T * BIN_E)                      // 4096
#define CLUS_CAP 12288                                 // 48KB LDS adj slice

typedef __attribute__((ext_vector_type(8))) short short8;
typedef __attribute__((ext_vector_type(4))) float f32x4;
typedef __attribute__((ext_vector_type(4))) int   int4v;

// ---------------- bf16 (storage) <-> f32 (math) ----------------

__device__ inline unsigned short f2bf(float v) {
    unsigned int b; __builtin_memcpy(&b, &v, 4);
    return (unsigned short)((b + 0x7FFFu + ((b >> 16) & 1u)) >> 16);   // RNE
}
__device__ inline float bf2f(unsigned short u) {
    return __uint_as_float(((unsigned int)u) << 16);
}
__device__ inline void sth(unsigned short* p, float v) { *p = f2bf(v); }
__device__ inline float bflo(unsigned int d) { return __uint_as_float(d << 16); }
__device__ inline float bfhi(unsigned int d) { return __uint_as_float(d & 0xFFFF0000u); }

__device__ inline int clampi(int v, int lo, int hi) {
    return v < lo ? lo : (v > hi ? hi : v);
}

// ---------------- utility ----------------

__global__ void k_zero(int* __restrict__ p, int n) {
    int i = blockIdx.x * blockDim.x + threadIdx.x;
    if (i < n) p[i] = 0;
}

__global__ void k_curinit(int* __restrict__ gcur) {
    int b = blockIdx.x * blockDim.x + threadIdx.x;
    if (b < NBUCK) gcur[b] = b * CAP;
}

// zero the sentinel row (node index N_NODES) of every quarter, both buffers
__global__ void k_zrow(uint2* __restrict__ hA, uint2* __restrict__ hB) {
    int t = threadIdx.x;
    uint2 z; z.x = 0u; z.y = 0u;
    if (t < 16)       hA[((size_t)(t >> 2) * NROWS + N_NODES) * 4 + (t & 3)] = z;
    else if (t < 32) { int u = t - 16;
                      hB[((size_t)(u >> 2) * NROWS + N_NODES) * 4 + (u & 3)] = z; }
}

// ---------------- CSR build: bin (slack buckets) + cluster (padded) ----------

__global__ __launch_bounds__(BIN_T) void k_bin(
        const int* __restrict__ ei, int* __restrict__ gcur,
        unsigned* __restrict__ pairs) {
    __shared__ int hist[NBUCK];
    __shared__ int base[NBUCK];
    for (int i = threadIdx.x; i < NBUCK; i += BIN_T) hist[i] = 0;
    __syncthreads();
    int e0 = blockIdx.x * BIN_CHUNK + threadIdx.x * BIN_E;
    int d[BIN_E], s[BIN_E];
    if (e0 + BIN_E <= N_EDGES) {
        const int4v* s4 = (const int4v*)ei;
        const int4v* d4 = (const int4v*)(ei + N_EDGES);
        #pragma unroll
        for (int q = 0; q < 4; ++q) {
            int4v dv = d4[(e0 >> 2) + q];
            int4v sv = s4[(e0 >> 2) + q];
            #pragma unroll
            for (int j = 0; j < 4; ++j) {
                d[q * 4 + j] = clampi(dv[j], 0, N_NODES - 1);
                s[q * 4 + j] = clampi(sv[j], 0, N_NODES - 1);
            }
        }
        #pragma unroll
        for (int k = 0; k < BIN_E; ++k) atomicAdd(&hist[d[k] >> BUCK_LOG], 1);
    } else {
        for (int k = 0; k < BIN_E; ++k) {
            int e = e0 + k;
            bool v = e < N_EDGES;
            d[k] = v ? clampi(ei[N_EDGES + e], 0, N_NODES - 1) : -1;
            s[k] = v ? clampi(ei[e], 0, N_NODES - 1) : 0;
            if (v) atomicAdd(&hist[d[k] >> BUCK_LOG], 1);
        }
    }
    __syncthreads();
    for (int i = threadIdx.x; i < NBUCK; i += BIN_T) {
        int c = hist[i];
        base[i] = c ? atomicAdd(&gcur[i], c) : 0;
        hist[i] = 0;                         // reuse as local rank
    }
    __syncthreads();
    #pragma unroll
    for (int k = 0; k < BIN_E; ++k) {
        if (d[k] >= 0) {
            int bk = d[k] >> BUCK_LOG;
            int r = atomicAdd(&hist[bk], 1);
            int idx = base[bk] + r;
            if (idx < (bk + 1) * CAP)
                pairs[idx] = ((unsigned)(d[k] & (BUCK_SZ - 1)) << 24) | (unsigned)s[k];
        }
    }
}

__global__ __launch_bounds__(512) void k_cluster(
        const unsigned* __restrict__ pairs, const int* __restrict__ gcur,
        int* __restrict__ poff, int* __restrict__ adj) {
    __shared__ int ladj[CLUS_CAP];
    __shared__ int lcur[BUCK_SZ];
    __shared__ int lsc[BUCK_SZ];
    __shared__ int ptot;
    int b  = blockIdx.x;
    int lo = b * BUCK_SZ;
    int nn = N_NODES - lo; if (nn > BUCK_SZ) nn = BUCK_SZ;
    int e0 = b * CAP;
    int cnt = gcur[b] - e0; if (cnt > CAP) cnt = CAP;
    int t = threadIdx.x;
    if (t < BUCK_SZ) lcur[t] = 0;
    __syncthreads();
    for (int i = t; i < cnt; i += 512) atomicAdd(&lcur[pairs[e0 + i] >> 24], 1);
    __syncthreads();
    int deg = 0, pdeg = 0;
    if (t < BUCK_SZ) {
        deg  = lcur[t];
        pdeg = (deg + 15) & ~15;
        if (pdeg > 2032) pdeg = 2032;        // nch fits 7 bits (never expected)
        lsc[t] = pdeg;
    }
    __syncthreads();
    #pragma unroll
    for (int d = 1; d < BUCK_SZ; d <<= 1) {
        int add = 0;
        if (t < BUCK_SZ && t >= d) add = lsc[t - d];
        __syncthreads();
        if (t < BUCK_SZ) lsc[t] += add;
        __syncthreads();
    }
    if (t == BUCK_SZ - 1) ptot = lsc[t];
    if (t < BUCK_SZ) {
        int exc = lsc[t] - pdeg;
        if (t < nn) poff[lo + t] = (e0 + exc) | ((pdeg >> 4) << 24);
        lcur[t] = exc;
    }
    __syncthreads();
    int pt = ptot;
    if (pt <= CLUS_CAP) {
        for (int i = t; i < pt; i += 512) ladj[i] = N_NODES;
        __syncthreads();
        for (int i = t; i < cnt; i += 512) {
            unsigned p = pairs[e0 + i];
            int pos = atomicAdd(&lcur[p >> 24], 1);
            ladj[pos] = (int)(p & 0xFFFFFFu);
        }
        __syncthreads();
        for (int i = t; i < pt; i += 512) adj[e0 + i] = ladj[i];
    } else {                                  // safety fallback (never expected)
        for (int i = t; i < pt && i < CAP + 4096; i += 512) adj[e0 + i] = N_NODES;
        __syncthreads();
        for (int i = t; i < cnt; i += 512) {
            unsigned p = pairs[e0 + i];
            int pos = atomicAdd(&lcur[p >> 24], 1);
            if (pos < CAP + 4096) adj[e0 + pos] = (int)(p & 0xFFFFFFu);
        }
    }
}

// ---------------- Layer 1 (F_IN = 3): fused agg + 3x64 matmul ----------------
// Output in quarter-major layout hout[q][node][16].

__global__ __launch_bounds__(256) void k_layer1(
        const float* __restrict__ x, const int* __restrict__ poff,
        const int* __restrict__ adj, const float* __restrict__ epsp,
        const float* __restrict__ W1, const float* __restrict__ b1,
        unsigned short* __restrict__ hout) {
    int wid  = (blockIdx.x * blockDim.x + threadIdx.x) >> 6;   // node
    int lane = threadIdx.x & 63;
    if (wid >= N_NODES) return;
    int pk = poff[wid];
    int st = pk & 0xFFFFFF;
    int n16 = ((unsigned)pk >> 24) << 4;
    float a0 = 0.f, a1 = 0.f, a2 = 0.f;
    for (int e = lane; e < n16; e += 64) {
        int s = adj[st + e];
        bool ok = s < N_NODES;
        int sc = ok ? s : 0;
        float m = ok ? 1.f : 0.f;
        a0 += m * x[sc * 3 + 0];
        a1 += m * x[sc * 3 + 1];
        a2 += m * x[sc * 3 + 2];
    }
    #pragma unroll
    for (int d = 32; d; d >>= 1) {
        a0 += __shfl_xor(a0, d);
        a1 += __shfl_xor(a1, d);
        a2 += __shfl_xor(a2, d);
    }
    float ep = 1.0f + epsp[0];
    float s0 = ep * x[wid * 3 + 0] + a0;
    float s1 = ep * x[wid * 3 + 1] + a1;
    float s2 = ep * x[wid * 3 + 2] + a2;
    float o = b1[lane] + s0 * W1[lane] + s1 * W1[64 + lane] + s2 * W1[128 + lane];
    hout[((size_t)(lane >> 4) * NROWS + wid) * 16 + (lane & 15)] = f2bf(fmaxf(o, 0.f));
}

// ---------------- Dense GEMM: Y = h @ W, quarter-major in/out ---------------

__global__ __launch_bounds__(256) void k_gemm(
        const unsigned short* __restrict__ hin, const float* __restrict__ W,
        unsigned short* __restrict__ Y) {
    int lane = threadIdx.x & 63;
    int r = lane & 15;
    int g = lane >> 4;
    int wave   = blockIdx.x * (blockDim.x >> 6) + (threadIdx.x >> 6);
    int nwaves = gridDim.x * (blockDim.x >> 6);

    short8 bh[2][4], bl[2][4];
    #pragma unroll
    for (int s = 0; s < 2; ++s) {
        #pragma unroll
        for (int t = 0; t < 4; ++t) {
            short8 hv, lv;
            #pragma unroll
            for (int i = 0; i < 8; ++i) {
                int k = s * 32 + g * 8 + i;
                int n = t * 16 + r;
                float w = W[k * 64 + n];
                unsigned short wh = f2bf(w);
                float whf = bf2f(wh);
                hv[i] = (short)wh;
                lv[i] = (short)f2bf(w - whf);
            }
            bh[s][t] = hv; bl[s][t] = lv;
        }
    }

    const int NT = N_NODES / 16;   // 6250 (exact)
    for (int mt = wave; mt < NT; mt += nwaves) {
        int row = mt * 16 + r;
        short8 a0 = *(const short8*)(hin + ((size_t)(g >> 1) * NROWS + row) * 16 + (g & 1) * 8);
        short8 a1 = *(const short8*)(hin + ((size_t)(2 + (g >> 1)) * NROWS + row) * 16 + (g & 1) * 8);
        #pragma unroll
        for (int t = 0; t < 4; ++t) {
            f32x4 acc = {0.f, 0.f, 0.f, 0.f};
            acc = __builtin_amdgcn_mfma_f32_16x16x32_bf16(a0, bh[0][t], acc, 0, 0, 0);
            acc = __builtin_amdgcn_mfma_f32_16x16x32_bf16(a0, bl[0][t], acc, 0, 0, 0);
            acc = __builtin_amdgcn_mfma_f32_16x16x32_bf16(a1, bh[1][t], acc, 0, 0, 0);
            acc = __builtin_amdgcn_mfma_f32_16x16x32_bf16(a1, bl[1][t], acc, 0, 0, 0);
            #pragma unroll
            for (int j = 0; j < 4; ++j) {
                sth(&Y[((size_t)t * NROWS + mt * 16 + g * 4 + j) * 16 + r], acc[j]);
            }
        }
    }
}

// ---------------- Quarter-sliced gather ------------------------------------
// One wave per (node, quarter). lane = nbr_group(lane>>2) x feat_quad(lane&3).
// Quarter q handled only by blocks with blockIdx%4==q (round-robin -> XCDs
// {q,q+4}), keeping the 3.2MB quarter L2-resident. adj reads non-temporal.

__device__ inline void gather_q(
        const uint2* __restrict__ h2, size_t qbase, int st, int nch,
        const int* __restrict__ adj, int kg, int fq,
        float& a0, float& a1, float& a2, float& a3) {
    for (int c = 0; c < nch; ++c) {
        int s = __builtin_nontemporal_load(adj + st + (c << 4) + kg);
        uint2 d = h2[qbase + (size_t)s * 4 + fq];
        a0 += bflo(d.x); a1 += bfhi(d.x);
        a2 += bflo(d.y); a3 += bfhi(d.y);
    }
    #pragma unroll
    for (int m = 4; m <= 32; m <<= 1) {
        a0 += __shfl_xor(a0, m);
        a1 += __shfl_xor(a1, m);
        a2 += __shfl_xor(a2, m);
        a3 += __shfl_xor(a3, m);
    }
}

__global__ __launch_bounds__(1024) void k_gather(
        const unsigned short* __restrict__ Y, const int* __restrict__ poff,
        const int* __restrict__ adj, const float* __restrict__ epsp,
        const float* __restrict__ b, unsigned short* __restrict__ hout) {
    int q     = blockIdx.x & 3;
    int chunk = blockIdx.x >> 2;
    int node  = chunk * 16 + (threadIdx.x >> 6);
    int lane  = threadIdx.x & 63;
    int pk = poff[node];
    int st = pk & 0xFFFFFF;
    int nch = (unsigned)pk >> 24;
    const uint2* h2 = (const uint2*)Y;
    size_t qbase = (size_t)q * NROWS * 4;
    float a0 = 0.f, a1 = 0.f, a2 = 0.f, a3 = 0.f;
    gather_q(h2, qbase, st, nch, adj, lane >> 2, lane & 3, a0, a1, a2, a3);
    if (lane < 4) {
        uint2 ds = h2[qbase + (size_t)node * 4 + lane];
        float ep = 1.0f + epsp[0];
        int fb = q * 16 + lane * 4;
        a0 = fmaxf(a0 + ep * bflo(ds.x) + b[fb + 0], 0.f);
        a1 = fmaxf(a1 + ep * bfhi(ds.x) + b[fb + 1], 0.f);
        a2 = fmaxf(a2 + ep * bflo(ds.y) + b[fb + 2], 0.f);
        a3 = fmaxf(a3 + ep * bfhi(ds.y) + b[fb + 3], 0.f);
        unsigned lo32 = (unsigned)f2bf(a0) | ((unsigned)f2bf(a1) << 16);
        unsigned hi32 = (unsigned)f2bf(a2) | ((unsigned)f2bf(a3) << 16);
        unsigned long long pk8 = ((unsigned long long)hi32 << 32) | lo32;
        __builtin_nontemporal_store(pk8,
            (unsigned long long*)hout + qbase + (size_t)node * 4 + lane);
    }
}

__global__ __launch_bounds__(1024) void k_gather_pool(
        const unsigned short* __restrict__ Y, const int* __restrict__ poff,
        const int* __restrict__ adj, const float* __restrict__ epsp,
        const float* __restrict__ b, const int* __restrict__ batch,
        float* __restrict__ pooled, int* __restrict__ cnt) {
    __shared__ float sacc[8 * 16];
    __shared__ int   scnt[8];
    if (threadIdx.x < 128) sacc[threadIdx.x] = 0.f;
    if (threadIdx.x < 8) scnt[threadIdx.x] = 0;
    __syncthreads();

    int q     = blockIdx.x & 3;
    int chunk = blockIdx.x >> 2;
    int node  = chunk * 16 + (threadIdx.x >> 6);
    int lane  = threadIdx.x & 63;
    int pk = poff[node];
    int st = pk & 0xFFFFFF;
    int nch = (unsigned)pk >> 24;
    const uint2* h2 = (const uint2*)Y;
    size_t qbase = (size_t)q * NROWS * 4;
    float a0 = 0.f, a1 = 0.f, a2 = 0.f, a3 = 0.f;
    gather_q(h2, qbase, st, nch, adj, lane >> 2, lane & 3, a0, a1, a2, a3);

    int g  = clampi(batch[node], 0, N_GRAPHS - 1);
    int g0 = clampi(batch[chunk * 16], 0, N_GRAPHS - 1);
    int og = g - g0;
    if (lane < 4) {
        uint2 ds = h2[qbase + (size_t)node * 4 + lane];
        float ep = 1.0f + epsp[0];
        int fb = q * 16 + lane * 4;
        a0 = fmaxf(a0 + ep * bflo(ds.x) + b[fb + 0], 0.f);
        a1 = fmaxf(a1 + ep * bfhi(ds.x) + b[fb + 1], 0.f);
        a2 = fmaxf(a2 + ep * bflo(ds.y) + b[fb + 2], 0.f);
        a3 = fmaxf(a3 + ep * bfhi(ds.y) + b[fb + 3], 0.f);
        if (og >= 0 && og < 8) {
            atomicAdd(&sacc[og * 16 + lane * 4 + 0], a0);
            atomicAdd(&sacc[og * 16 + lane * 4 + 1], a1);
            atomicAdd(&sacc[og * 16 + lane * 4 + 2], a2);
            atomicAdd(&sacc[og * 16 + lane * 4 + 3], a3);
        } else {
            atomicAdd(&pooled[g * 64 + q * 16 + lane * 4 + 0], a0);
            atomicAdd(&pooled[g * 64 + q * 16 + lane * 4 + 1], a1);
            atomicAdd(&pooled[g * 64 + q * 16 + lane * 4 + 2], a2);
            atomicAdd(&pooled[g * 64 + q * 16 + lane * 4 + 3], a3);
        }
    }
    if (q == 0 && lane == 0) {
        if (og >= 0 && og < 8) atomicAdd(&scnt[og], 1);
        else atomicAdd(&cnt[g], 1);
    }
    __syncthreads();
    int w = threadIdx.x >> 6;                // waves 0..7 flush slots
    if (w < 8) {
        if (lane < 16) {
            float v = sacc[w * 16 + lane];
            if (v != 0.f) atomicAdd(&pooled[(g0 + w) * 64 + q * 16 + lane], v);
        }
        if (q == 0 && lane == 0) {
            int c = scnt[w];
            if (c > 0) atomicAdd(&cnt[g0 + w], c);
        }
    }
}

// ---------------- Head: mean, 64->10 relu, 10->1 ----------------

__global__ __launch_bounds__(256) void k_head(
        const float* __restrict__ pooled, const int* __restrict__ cnt,
        const float* __restrict__ Wf1, const float* __restrict__ bf1,
        const float* __restrict__ Wf2, const float* __restrict__ bf2,
        float* __restrict__ out) {
    int g = blockIdx.x * blockDim.x + threadIdx.x;
    if (g >= N_GRAPHS) return;
    float inv = 1.0f / fmaxf((float)cnt[g], 1.0f);
    float p[64];
    #pragma unroll
    for (int k = 0; k < 64; ++k) p[k] = pooled[g * 64 + k] * inv;
    float o = bf2[0];
    #pragma unroll
    for (int j = 0; j < 10; ++j) {
        float s = bf1[j];
        #pragma unroll
        for (int k = 0; k < 64; ++k) s += p[k] * Wf1[k * 10 + j];
        o += fmaxf(s, 0.f) * Wf2[j];
    }
    out[g] = o;
}

// ---------------- launch ----------------

extern "C" void kernel_launch(void* const* d_in, const int* in_sizes, int n_in,
                              void* d_out, int out_size, void* d_ws, size_t ws_size,
                              hipStream_t stream) {
    const float* x     = (const float*)d_in[0];
    const int*   ei    = (const int*)d_in[1];    // int64 in ref -> int32 on device
    const int*   batch = (const int*)d_in[2];
    const float* eps1 = (const float*)d_in[3];
    const float* eps2 = (const float*)d_in[4];
    const float* eps3 = (const float*)d_in[5];
    const float* W1 = (const float*)d_in[6];
    const float* b1 = (const float*)d_in[7];
    const float* W2 = (const float*)d_in[8];
    const float* b2 = (const float*)d_in[9];
    const float* W3 = (const float*)d_in[10];
    const float* b3 = (const float*)d_in[11];
    const float* Wf1 = (const float*)d_in[12];
    const float* bf1 = (const float*)d_in[13];
    const float* Wf2 = (const float*)d_in[14];
    const float* bf2 = (const float*)d_in[15];
    float* out = (float*)d_out;

    const size_t HBYTES = (size_t)NROWS * HDIM * 2;     // 12.800128 MB

    char* base = (char*)d_ws;
    unsigned short* hA = (unsigned short*)base;
    unsigned short* hB = (unsigned short*)(base + HBYTES);
    unsigned* pairs = (unsigned*)base;   // 25.6 MB, aliases hA+hB (build only)
    char* q = base + 2 * HBYTES;
    float* pooled = (float*)q;            q += 64000ull * 4;
    int*   cnt    = (int*)q;              q += 1000ull * 4;
    int*   poff   = (int*)q;              q += 100000ull * 4;
    int*   gcur   = (int*)q;              q += 512ull * 4;
    int*   adj    = (int*)q;              // NBUCK*CAP + 4096 ints

    const int TB = 256;
    // CSR build: init cursors -> bin (packed pairs, slack buckets) -> cluster
    k_curinit<<<(NBUCK + TB - 1) / TB, TB, 0, stream>>>(gcur);
    const int BINB = (N_EDGES + BIN_CHUNK - 1) / BIN_CHUNK;   // 782
    k_bin<<<BINB, BIN_T, 0, stream>>>(ei, gcur, pairs);
    k_cluster<<<NBUCK, 512, 0, stream>>>(pairs, gcur, poff, adj);

    // pooled/cnt zero + sentinel rows (after pairs region is dead)
    k_zero<<<(65000 + TB - 1) / TB, TB, 0, stream>>>((int*)pooled, 65000);
    k_zrow<<<1, 64, 0, stream>>>((uint2*)hA, (uint2*)hB);

    const int L1_BLOCKS = (N_NODES * 64 + TB - 1) / TB;      // 4 nodes/block @256
    const int GQB = (N_NODES / 16) * 4;                      // 25000 (16 nodes x 4 quarters)

    // layer 1 (fused, cheap gathers of 12B x-rows) -> quarter-major hA
    k_layer1<<<L1_BLOCKS, TB, 0, stream>>>(x, poff, adj, eps1, W1, b1, hA);
    // layer 2: GEMM then quarter-sliced gather
    k_gemm<<<256, 256, 0, stream>>>(hA, W2, hB);
    k_gather<<<GQB, 1024, 0, stream>>>(hB, poff, adj, eps2, b2, hA);
    // layer 3: GEMM then quarter-sliced gather+pool
    k_gemm<<<256, 256, 0, stream>>>(hA, W3, hB);
    k_gather_pool<<<GQB, 1024, 0, stream>>>(hB, poff, adj, eps3, b3, batch, pooled, cnt);

    k_head<<<(N_GRAPHS + TB - 1) / TB, TB, 0, stream>>>(pooled, cnt, Wf1, bf1, Wf2, bf2, out);
}

// Round 18
// 454.888 us; speedup vs baseline: 1.0804x; 1.0804x over previous
//
#include <hip/hip_runtime.h>

#define N_NODES  100000
#define N_GRAPHS 1000
#define N_EDGES  3200000
#define HDIM     64
#define NROWS    (N_NODES + 1)                         // +1 sentinel zero row

#define BUCK_LOG 8
#define BUCK_SZ  256
#define NBUCK    ((N_NODES + BUCK_SZ - 1) / BUCK_SZ)   // 391
#define CAP      16384                                 // slack slots per bucket
#define BIN_T    256
#define BIN_E    16
#define BIN_CHUNK (BIN_T * BIN_E)                      // 4096
#define CLUS_CAP 12288                                 // 48KB LDS adj slice

typedef __attribute__((ext_vector_type(8))) short short8;
typedef __attribute__((ext_vector_type(4))) float f32x4;
typedef __attribute__((ext_vector_type(4))) int   int4v;

// ---------------- bf16 (storage) <-> f32 (math) ----------------

__device__ inline unsigned short f2bf(float v) {
    unsigned int b; __builtin_memcpy(&b, &v, 4);
    return (unsigned short)((b + 0x7FFFu + ((b >> 16) & 1u)) >> 16);   // RNE
}
__device__ inline float bf2f(unsigned short u) {
    return __uint_as_float(((unsigned int)u) << 16);
}
__device__ inline void sth(unsigned short* p, float v) { *p = f2bf(v); }
__device__ inline float bflo(unsigned int d) { return __uint_as_float(d << 16); }
__device__ inline float bfhi(unsigned int d) { return __uint_as_float(d & 0xFFFF0000u); }

__device__ inline int clampi(int v, int lo, int hi) {
    return v < lo ? lo : (v > hi ? hi : v);
}

// ---------------- utility ----------------

__global__ void k_zero(int* __restrict__ p, int n) {
    int i = blockIdx.x * blockDim.x + threadIdx.x;
    if (i < n) p[i] = 0;
}

__global__ void k_curinit(int* __restrict__ gcur) {
    int b = blockIdx.x * blockDim.x + threadIdx.x;
    if (b < NBUCK) gcur[b] = b * CAP;
}

// zero the sentinel row (node index N_NODES) of every quarter, both buffers
__global__ void k_zrow(uint2* __restrict__ hA, uint2* __restrict__ hB) {
    int t = threadIdx.x;
    uint2 z; z.x = 0u; z.y = 0u;
    if (t < 16)       hA[((size_t)(t >> 2) * NROWS + N_NODES) * 4 + (t & 3)] = z;
    else if (t < 32) { int u = t - 16;
                      hB[((size_t)(u >> 2) * NROWS + N_NODES) * 4 + (u & 3)] = z; }
}

// ---------------- CSR build: bin (slack buckets) + cluster (padded) ----------

__global__ __launch_bounds__(BIN_T) void k_bin(
        const int* __restrict__ ei, int* __restrict__ gcur,
        unsigned* __restrict__ pairs) {
    __shared__ int hist[NBUCK];
    __shared__ int base[NBUCK];
    for (int i = threadIdx.x; i < NBUCK; i += BIN_T) hist[i] = 0;
    __syncthreads();
    int e0 = blockIdx.x * BIN_CHUNK + threadIdx.x * BIN_E;
    int d[BIN_E], s[BIN_E];
    if (e0 + BIN_E <= N_EDGES) {
        const int4v* s4 = (const int4v*)ei;
        const int4v* d4 = (const int4v*)(ei + N_EDGES);
        #pragma unroll
        for (int q = 0; q < 4; ++q) {
            int4v dv = d4[(e0 >> 2) + q];
            int4v sv = s4[(e0 >> 2) + q];
            #pragma unroll
            for (int j = 0; j < 4; ++j) {
                d[q * 4 + j] = clampi(dv[j], 0, N_NODES - 1);
                s[q * 4 + j] = clampi(sv[j], 0, N_NODES - 1);
            }
        }
        #pragma unroll
        for (int k = 0; k < BIN_E; ++k) atomicAdd(&hist[d[k] >> BUCK_LOG], 1);
    } else {
        for (int k = 0; k < BIN_E; ++k) {
            int e = e0 + k;
            bool v = e < N_EDGES;
            d[k] = v ? clampi(ei[N_EDGES + e], 0, N_NODES - 1) : -1;
            s[k] = v ? clampi(ei[e], 0, N_NODES - 1) : 0;
            if (v) atomicAdd(&hist[d[k] >> BUCK_LOG], 1);
        }
    }
    __syncthreads();
    for (int i = threadIdx.x; i < NBUCK; i += BIN_T) {
        int c = hist[i];
        base[i] = c ? atomicAdd(&gcur[i], c) : 0;
        hist[i] = 0;                         // reuse as local rank
    }
    __syncthreads();
    #pragma unroll
    for (int k = 0; k < BIN_E; ++k) {
        if (d[k] >= 0) {
            int bk = d[k] >> BUCK_LOG;
            int r = atomicAdd(&hist[bk], 1);
            int idx = base[bk] + r;
            if (idx < (bk + 1) * CAP)
                pairs[idx] = ((unsigned)(d[k] & (BUCK_SZ - 1)) << 24) | (unsigned)s[k];
        }
    }
}

__global__ __launch_bounds__(512) void k_cluster(
        const unsigned* __restrict__ pairs, const int* __restrict__ gcur,
        int* __restrict__ poff, int* __restrict__ adj) {
    __shared__ int ladj[CLUS_CAP];
    __shared__ int lcur[BUCK_SZ];
    __shared__ int lsc[BUCK_SZ];
    __shared__ int ptot;
    int b  = blockIdx.x;
    int lo = b * BUCK_SZ;
    int nn = N_NODES - lo; if (nn > BUCK_SZ) nn = BUCK_SZ;
    int e0 = b * CAP;
    int cnt = gcur[b] - e0; if (cnt > CAP) cnt = CAP;
    int t = threadIdx.x;
    if (t < BUCK_SZ) lcur[t] = 0;
    __syncthreads();
    for (int i = t; i < cnt; i += 512) atomicAdd(&lcur[pairs[e0 + i] >> 24], 1);
    __syncthreads();
    int deg = 0, pdeg = 0;
    if (t < BUCK_SZ) {
        deg  = lcur[t];
        pdeg = (deg + 15) & ~15;
        if (pdeg > 2032) pdeg = 2032;        // nch fits 7 bits (never expected)
        lsc[t] = pdeg;
    }
    __syncthreads();
    #pragma unroll
    for (int d = 1; d < BUCK_SZ; d <<= 1) {
        int add = 0;
        if (t < BUCK_SZ && t >= d) add = lsc[t - d];
        __syncthreads();
        if (t < BUCK_SZ) lsc[t] += add;
        __syncthreads();
    }
    if (t == BUCK_SZ - 1) ptot = lsc[t];
    if (t < BUCK_SZ) {
        int exc = lsc[t] - pdeg;
        if (t < nn) poff[lo + t] = (e0 + exc) | ((pdeg >> 4) << 24);
        lcur[t] = exc;
    }
    __syncthreads();
    int pt = ptot;
    if (pt <= CLUS_CAP) {
        for (int i = t; i < pt; i += 512) ladj[i] = N_NODES;
        __syncthreads();
        for (int i = t; i < cnt; i += 512) {
            unsigned p = pairs[e0 + i];
            int pos = atomicAdd(&lcur[p >> 24], 1);
            ladj[pos] = (int)(p & 0xFFFFFFu);
        }
        __syncthreads();
        for (int i = t; i < pt; i += 512) adj[e0 + i] = ladj[i];
    } else {                                  // safety fallback (never expected)
        for (int i = t; i < pt && i < CAP + 4096; i += 512) adj[e0 + i] = N_NODES;
        __syncthreads();
        for (int i = t; i < cnt; i += 512) {
            unsigned p = pairs[e0 + i];
            int pos = atomicAdd(&lcur[p >> 24], 1);
            if (pos < CAP + 4096) adj[e0 + pos] = (int)(p & 0xFFFFFFu);
        }
    }
}

// ---------------- Layer 1 (F_IN = 3): fused agg + 3x64 matmul ----------------
// Output in quarter-major layout hout[q][node][16].

__global__ __launch_bounds__(256) void k_layer1(
        const float* __restrict__ x, const int* __restrict__ poff,
        const int* __restrict__ adj, const float* __restrict__ epsp,
        const float* __restrict__ W1, const float* __restrict__ b1,
        unsigned short* __restrict__ hout) {
    int wid  = (blockIdx.x * blockDim.x + threadIdx.x) >> 6;   // node
    int lane = threadIdx.x & 63;
    if (wid >= N_NODES) return;
    int pk = poff[wid];
    int st = pk & 0xFFFFFF;
    int n16 = ((unsigned)pk >> 24) << 4;
    float a0 = 0.f, a1 = 0.f, a2 = 0.f;
    for (int e = lane; e < n16; e += 64) {
        int s = adj[st + e];
        bool ok = s < N_NODES;
        int sc = ok ? s : 0;
        float m = ok ? 1.f : 0.f;
        a0 += m * x[sc * 3 + 0];
        a1 += m * x[sc * 3 + 1];
        a2 += m * x[sc * 3 + 2];
    }
    #pragma unroll
    for (int d = 32; d; d >>= 1) {
        a0 += __shfl_xor(a0, d);
        a1 += __shfl_xor(a1, d);
        a2 += __shfl_xor(a2, d);
    }
    float ep = 1.0f + epsp[0];
    float s0 = ep * x[wid * 3 + 0] + a0;
    float s1 = ep * x[wid * 3 + 1] + a1;
    float s2 = ep * x[wid * 3 + 2] + a2;
    float o = b1[lane] + s0 * W1[lane] + s1 * W1[64 + lane] + s2 * W1[128 + lane];
    hout[((size_t)(lane >> 4) * NROWS + wid) * 16 + (lane & 15)] = f2bf(fmaxf(o, 0.f));
}

// ---------------- Dense GEMM: Y = h @ W, quarter-major in/out ---------------

__global__ __launch_bounds__(256) void k_gemm(
        const unsigned short* __restrict__ hin, const float* __restrict__ W,
        unsigned short* __restrict__ Y) {
    int lane = threadIdx.x & 63;
    int r = lane & 15;
    int g = lane >> 4;
    int wave   = blockIdx.x * (blockDim.x >> 6) + (threadIdx.x >> 6);
    int nwaves = gridDim.x * (blockDim.x >> 6);

    short8 bh[2][4], bl[2][4];
    #pragma unroll
    for (int s = 0; s < 2; ++s) {
        #pragma unroll
        for (int t = 0; t < 4; ++t) {
            short8 hv, lv;
            #pragma unroll
            for (int i = 0; i < 8; ++i) {
                int k = s * 32 + g * 8 + i;
                int n = t * 16 + r;
                float w = W[k * 64 + n];
                unsigned short wh = f2bf(w);
                float whf = bf2f(wh);
                hv[i] = (short)wh;
                lv[i] = (short)f2bf(w - whf);
            }
            bh[s][t] = hv; bl[s][t] = lv;
        }
    }

    const int NT = N_NODES / 16;   // 6250 (exact)
    for (int mt = wave; mt < NT; mt += nwaves) {
        int row = mt * 16 + r;
        short8 a0 = *(const short8*)(hin + ((size_t)(g >> 1) * NROWS + row) * 16 + (g & 1) * 8);
        short8 a1 = *(const short8*)(hin + ((size_t)(2 + (g >> 1)) * NROWS + row) * 16 + (g & 1) * 8);
        #pragma unroll
        for (int t = 0; t < 4; ++t) {
            f32x4 acc = {0.f, 0.f, 0.f, 0.f};
            acc = __builtin_amdgcn_mfma_f32_16x16x32_bf16(a0, bh[0][t], acc, 0, 0, 0);
            acc = __builtin_amdgcn_mfma_f32_16x16x32_bf16(a0, bl[0][t], acc, 0, 0, 0);
            acc = __builtin_amdgcn_mfma_f32_16x16x32_bf16(a1, bh[1][t], acc, 0, 0, 0);
            acc = __builtin_amdgcn_mfma_f32_16x16x32_bf16(a1, bl[1][t], acc, 0, 0, 0);
            #pragma unroll
            for (int j = 0; j < 4; ++j) {
                sth(&Y[((size_t)t * NROWS + mt * 16 + g * 4 + j) * 16 + r], acc[j]);
            }
        }
    }
}

// ---------------- Quarter-sliced gather with 4-deep ILP ----------------------
// One wave per (node, quarter). lane = nbr_group(lane>>2) x feat_quad(lane&3).
// Quarter q handled by blocks with blockIdx%4==q (round-robin -> 2 XCDs own
// each 3.2MB quarter, L2-resident). adj reads non-temporal. 4 chunks per
// outer iteration: 4 independent adj loads then 4 independent gathers.

__device__ inline void gather_q(
        const uint2* __restrict__ h2, size_t qbase, int st, int nch,
        const int* __restrict__ adj, int kg, int fq,
        float& a0, float& a1, float& a2, float& a3) {
    for (int c = 0; c < nch; c += 4) {
        int a[4];
        #pragma unroll
        for (int i = 0; i < 4; ++i) {
            int cc = c + i;
            int pos = st + (cc << 4) + kg;
            int posc = (cc < nch) ? pos : (st + kg);   // safe re-read of chunk 0
            a[i] = __builtin_nontemporal_load(adj + posc);
        }
        uint2 dd[4];
        #pragma unroll
        for (int i = 0; i < 4; ++i) {
            int s = ((c + i) < nch) ? a[i] : N_NODES;  // sentinel -> zero row
            dd[i] = h2[qbase + (size_t)s * 4 + fq];
        }
        #pragma unroll
        for (int i = 0; i < 4; ++i) {
            a0 += bflo(dd[i].x); a1 += bfhi(dd[i].x);
            a2 += bflo(dd[i].y); a3 += bfhi(dd[i].y);
        }
    }
    #pragma unroll
    for (int m = 4; m <= 32; m <<= 1) {
        a0 += __shfl_xor(a0, m);
        a1 += __shfl_xor(a1, m);
        a2 += __shfl_xor(a2, m);
        a3 += __shfl_xor(a3, m);
    }
}

__global__ __launch_bounds__(1024) void k_gather(
        const unsigned short* __restrict__ Y, const int* __restrict__ poff,
        const int* __restrict__ adj, const float* __restrict__ epsp,
        const float* __restrict__ b, unsigned short* __restrict__ hout) {
    int q     = blockIdx.x & 3;
    int chunk = blockIdx.x >> 2;
    int node  = chunk * 16 + (threadIdx.x >> 6);
    int lane  = threadIdx.x & 63;
    int pk = poff[node];
    int st = pk & 0xFFFFFF;
    int nch = (unsigned)pk >> 24;
    const uint2* h2 = (const uint2*)Y;
    size_t qbase = (size_t)q * NROWS * 4;
    float a0 = 0.f, a1 = 0.f, a2 = 0.f, a3 = 0.f;
    gather_q(h2, qbase, st, nch, adj, lane >> 2, lane & 3, a0, a1, a2, a3);
    if (lane < 4) {
        uint2 ds = h2[qbase + (size_t)node * 4 + lane];
        float ep = 1.0f + epsp[0];
        int fb = q * 16 + lane * 4;
        a0 = fmaxf(a0 + ep * bflo(ds.x) + b[fb + 0], 0.f);
        a1 = fmaxf(a1 + ep * bfhi(ds.x) + b[fb + 1], 0.f);
        a2 = fmaxf(a2 + ep * bflo(ds.y) + b[fb + 2], 0.f);
        a3 = fmaxf(a3 + ep * bfhi(ds.y) + b[fb + 3], 0.f);
        unsigned lo32 = (unsigned)f2bf(a0) | ((unsigned)f2bf(a1) << 16);
        unsigned hi32 = (unsigned)f2bf(a2) | ((unsigned)f2bf(a3) << 16);
        unsigned long long pk8 = ((unsigned long long)hi32 << 32) | lo32;
        __builtin_nontemporal_store(pk8,
            (unsigned long long*)hout + qbase + (size_t)node * 4 + lane);
    }
}

__global__ __launch_bounds__(1024) void k_gather_pool(
        const unsigned short* __restrict__ Y, const int* __restrict__ poff,
        const int* __restrict__ adj, const float* __restrict__ epsp,
        const float* __restrict__ b, const int* __restrict__ batch,
        float* __restrict__ pooled, int* __restrict__ cnt) {
    __shared__ float sacc[8 * 16];
    __shared__ int   scnt[8];
    if (threadIdx.x < 128) sacc[threadIdx.x] = 0.f;
    if (threadIdx.x < 8) scnt[threadIdx.x] = 0;
    __syncthreads();

    int q     = blockIdx.x & 3;
    int chunk = blockIdx.x >> 2;
    int node  = chunk * 16 + (threadIdx.x >> 6);
    int lane  = threadIdx.x & 63;
    int pk = poff[node];
    int st = pk & 0xFFFFFF;
    int nch = (unsigned)pk >> 24;
    const uint2* h2 = (const uint2*)Y;
    size_t qbase = (size_t)q * NROWS * 4;
    float a0 = 0.f, a1 = 0.f, a2 = 0.f, a3 = 0.f;
    gather_q(h2, qbase, st, nch, adj, lane >> 2, lane & 3, a0, a1, a2, a3);

    int g  = clampi(batch[node], 0, N_GRAPHS - 1);
    int g0 = clampi(batch[chunk * 16], 0, N_GRAPHS - 1);
    int og = g - g0;
    if (lane < 4) {
        uint2 ds = h2[qbase + (size_t)node * 4 + lane];
        float ep = 1.0f + epsp[0];
        int fb = q * 16 + lane * 4;
        a0 = fmaxf(a0 + ep * bflo(ds.x) + b[fb + 0], 0.f);
        a1 = fmaxf(a1 + ep * bfhi(ds.x) + b[fb + 1], 0.f);
        a2 = fmaxf(a2 + ep * bflo(ds.y) + b[fb + 2], 0.f);
        a3 = fmaxf(a3 + ep * bfhi(ds.y) + b[fb + 3], 0.f);
        if (og >= 0 && og < 8) {
            atomicAdd(&sacc[og * 16 + lane * 4 + 0], a0);
            atomicAdd(&sacc[og * 16 + lane * 4 + 1], a1);
            atomicAdd(&sacc[og * 16 + lane * 4 + 2], a2);
            atomicAdd(&sacc[og * 16 + lane * 4 + 3], a3);
        } else {
            atomicAdd(&pooled[g * 64 + q * 16 + lane * 4 + 0], a0);
            atomicAdd(&pooled[g * 64 + q * 16 + lane * 4 + 1], a1);
            atomicAdd(&pooled[g * 64 + q * 16 + lane * 4 + 2], a2);
            atomicAdd(&pooled[g * 64 + q * 16 + lane * 4 + 3], a3);
        }
    }
    if (q == 0 && lane == 0) {
        if (og >= 0 && og < 8) atomicAdd(&scnt[og], 1);
        else atomicAdd(&cnt[g], 1);
    }
    __syncthreads();
    int w = threadIdx.x >> 6;                // waves 0..7 flush slots
    if (w < 8) {
        if (lane < 16) {
            float v = sacc[w * 16 + lane];
            if (v != 0.f) atomicAdd(&pooled[(g0 + w) * 64 + q * 16 + lane], v);
        }
        if (q == 0 && lane == 0) {
            int c = scnt[w];
            if (c > 0) atomicAdd(&cnt[g0 + w], c);
        }
    }
}

// ---------------- Head: mean, 64->10 relu, 10->1 ----------------

__global__ __launch_bounds__(256) void k_head(
        const float* __restrict__ pooled, const int* __restrict__ cnt,
        const float* __restrict__ Wf1, const float* __restrict__ bf1,
        const float* __restrict__ Wf2, const float* __restrict__ bf2,
        float* __restrict__ out) {
    int g = blockIdx.x * blockDim.x + threadIdx.x;
    if (g >= N_GRAPHS) return;
    float inv = 1.0f / fmaxf((float)cnt[g], 1.0f);
    float p[64];
    #pragma unroll
    for (int k = 0; k < 64; ++k) p[k] = pooled[g * 64 + k] * inv;
    float o = bf2[0];
    #pragma unroll
    for (int j = 0; j < 10; ++j) {
        float s = bf1[j];
        #pragma unroll
        for (int k = 0; k < 64; ++k) s += p[k] * Wf1[k * 10 + j];
        o += fmaxf(s, 0.f) * Wf2[j];
    }
    out[g] = o;
}

// ---------------- launch ----------------

extern "C" void kernel_launch(void* const* d_in, const int* in_sizes, int n_in,
                              void* d_out, int out_size, void* d_ws, size_t ws_size,
                              hipStream_t stream) {
    const float* x     = (const float*)d_in[0];
    const int*   ei    = (const int*)d_in[1];    // int64 in ref -> int32 on device
    const int*   batch = (const int*)d_in[2];
    const float* eps1 = (const float*)d_in[3];
    const float* eps2 = (const float*)d_in[4];
    const float* eps3 = (const float*)d_in[5];
    const float* W1 = (const float*)d_in[6];
    const float* b1 = (const float*)d_in[7];
    const float* W2 = (const float*)d_in[8];
    const float* b2 = (const float*)d_in[9];
    const float* W3 = (const float*)d_in[10];
    const float* b3 = (const float*)d_in[11];
    const float* Wf1 = (const float*)d_in[12];
    const float* bf1 = (const float*)d_in[13];
    const float* Wf2 = (const float*)d_in[14];
    const float* bf2 = (const float*)d_in[15];
    float* out = (float*)d_out;

    const size_t HBYTES = (size_t)NROWS * HDIM * 2;     // 12.800128 MB

    char* base = (char*)d_ws;
    unsigned short* hA = (unsigned short*)base;
    unsigned short* hB = (unsigned short*)(base + HBYTES);
    unsigned* pairs = (unsigned*)base;   // 25.6 MB, aliases hA+hB (build only)
    char* q = base + 2 * HBYTES;
    float* pooled = (float*)q;            q += 64000ull * 4;
    int*   cnt    = (int*)q;              q += 1000ull * 4;
    int*   poff   = (int*)q;              q += 100000ull * 4;
    int*   gcur   = (int*)q;              q += 512ull * 4;
    int*   adj    = (int*)q;              // NBUCK*CAP + 4096 ints

    const int TB = 256;
    // CSR build: init cursors -> bin (packed pairs, slack buckets) -> cluster
    k_curinit<<<(NBUCK + TB - 1) / TB, TB, 0, stream>>>(gcur);
    const int BINB = (N_EDGES + BIN_CHUNK - 1) / BIN_CHUNK;   // 782
    k_bin<<<BINB, BIN_T, 0, stream>>>(ei, gcur, pairs);
    k_cluster<<<NBUCK, 512, 0, stream>>>(pairs, gcur, poff, adj);

    // pooled/cnt zero + sentinel rows (after pairs region is dead)
    k_zero<<<(65000 + TB - 1) / TB, TB, 0, stream>>>((int*)pooled, 65000);
    k_zrow<<<1, 64, 0, stream>>>((uint2*)hA, (uint2*)hB);

    const int L1_BLOCKS = (N_NODES * 64 + TB - 1) / TB;      // 4 nodes/block @256
    const int GQB = (N_NODES / 16) * 4;                      // 25000 (16 nodes x 4 quarters)

    // layer 1 (fused, cheap gathers of 12B x-rows) -> quarter-major hA
    k_layer1<<<L1_BLOCKS, TB, 0, stream>>>(x, poff, adj, eps1, W1, b1, hA);
    // layer 2: GEMM then quarter-sliced gather
    k_gemm<<<256, 256, 0, stream>>>(hA, W2, hB);
    k_gather<<<GQB, 1024, 0, stream>>>(hB, poff, adj, eps2, b2, hA);
    // layer 3: GEMM then quarter-sliced gather+pool
    k_gemm<<<256, 256, 0, stream>>>(hA, W3, hB);
    k_gather_pool<<<GQB, 1024, 0, stream>>>(hB, poff, adj, eps3, b3, batch, pooled, cnt);

    k_head<<<(N_GRAPHS + TB - 1) / TB, TB, 0, stream>>>(pooled, cnt, Wf1, bf1, Wf2, bf2, out);
}

// Round 19
// 241.820 us; speedup vs baseline: 2.0324x; 1.8811x over previous
//
#include <hip/hip_runtime.h>

#define N_NODES  100000
#define N_GRAPHS 1000
#define N_EDGES  3200000
#define HDIM     64

#define BUCK_LOG 8
#define BUCK_SZ  256
#define NBUCK    ((N_NODES + BUCK_SZ - 1) / BUCK_SZ)   // 391
#define CAP      16384                                 // slack slots per bucket
#define BIN_T    256
#define BIN_E    16
#define BIN_CHUNK (BIN_T * BIN_E)                      // 4096
#define CLUS_CAP 12288                                 // 48KB LDS adj slice

typedef __attribute__((ext_vector_type(8))) short short8;
typedef __attribute__((ext_vector_type(4))) float f32x4;
typedef __attribute__((ext_vector_type(4))) int   int4v;

// ---------------- bf16 (storage) <-> f32 (math) ----------------

__device__ inline unsigned short f2bf(float v) {
    unsigned int b; __builtin_memcpy(&b, &v, 4);
    return (unsigned short)((b + 0x7FFFu + ((b >> 16) & 1u)) >> 16);   // RNE
}
__device__ inline float bf2f(unsigned short u) {
    return __uint_as_float(((unsigned int)u) << 16);
}
__device__ inline void sth(unsigned short* p, float v) { *p = f2bf(v); }
__device__ inline float bflo(unsigned int d) { return __uint_as_float(d << 16); }
__device__ inline float bfhi(unsigned int d) { return __uint_as_float(d & 0xFFFF0000u); }

__device__ inline int clampi(int v, int lo, int hi) {
    return v < lo ? lo : (v > hi ? hi : v);
}

// ---------------- utility ----------------

__global__ void k_zero(int* __restrict__ p, int n) {
    int i = blockIdx.x * blockDim.x + threadIdx.x;
    if (i < n) p[i] = 0;
}

__global__ void k_curinit(int* __restrict__ gcur) {
    int b = blockIdx.x * blockDim.x + threadIdx.x;
    if (b < NBUCK) gcur[b] = b * CAP;
}

// zero the sentinel feature row (index N_NODES) of both h buffers
__global__ void k_zrow(uint2* __restrict__ hA, uint2* __restrict__ hB) {
    int t = threadIdx.x;
    uint2 z; z.x = 0u; z.y = 0u;
    if (t < 16)       hA[(size_t)N_NODES * 16 + t] = z;
    else if (t < 32)  hB[(size_t)N_NODES * 16 + (t - 16)] = z;
}

// ---------------- CSR build: bin (slack buckets) + cluster (padded) ----------

__global__ __launch_bounds__(BIN_T) void k_bin(
        const int* __restrict__ ei, int* __restrict__ gcur,
        unsigned* __restrict__ pairs) {
    __shared__ int hist[NBUCK];
    __shared__ int base[NBUCK];
    for (int i = threadIdx.x; i < NBUCK; i += BIN_T) hist[i] = 0;
    __syncthreads();
    int e0 = blockIdx.x * BIN_CHUNK + threadIdx.x * BIN_E;
    int d[BIN_E], s[BIN_E];
    if (e0 + BIN_E <= N_EDGES) {
        const int4v* s4 = (const int4v*)ei;
        const int4v* d4 = (const int4v*)(ei + N_EDGES);
        #pragma unroll
        for (int q = 0; q < 4; ++q) {
            int4v dv = d4[(e0 >> 2) + q];
            int4v sv = s4[(e0 >> 2) + q];
            #pragma unroll
            for (int j = 0; j < 4; ++j) {
                d[q * 4 + j] = clampi(dv[j], 0, N_NODES - 1);
                s[q * 4 + j] = clampi(sv[j], 0, N_NODES - 1);
            }
        }
        #pragma unroll
        for (int k = 0; k < BIN_E; ++k) atomicAdd(&hist[d[k] >> BUCK_LOG], 1);
    } else {
        for (int k = 0; k < BIN_E; ++k) {
            int e = e0 + k;
            bool v = e < N_EDGES;
            d[k] = v ? clampi(ei[N_EDGES + e], 0, N_NODES - 1) : -1;
            s[k] = v ? clampi(ei[e], 0, N_NODES - 1) : 0;
            if (v) atomicAdd(&hist[d[k] >> BUCK_LOG], 1);
        }
    }
    __syncthreads();
    for (int i = threadIdx.x; i < NBUCK; i += BIN_T) {
        int c = hist[i];
        base[i] = c ? atomicAdd(&gcur[i], c) : 0;
        hist[i] = 0;                         // reuse as local rank
    }
    __syncthreads();
    #pragma unroll
    for (int k = 0; k < BIN_E; ++k) {
        if (d[k] >= 0) {
            int bk = d[k] >> BUCK_LOG;
            int r = atomicAdd(&hist[bk], 1);
            int idx = base[bk] + r;
            if (idx < (bk + 1) * CAP)
                pairs[idx] = ((unsigned)(d[k] & (BUCK_SZ - 1)) << 24) | (unsigned)s[k];
        }
    }
}

__global__ __launch_bounds__(512) void k_cluster(
        const unsigned* __restrict__ pairs, const int* __restrict__ gcur,
        int* __restrict__ poff, int* __restrict__ adj) {
    __shared__ int ladj[CLUS_CAP];
    __shared__ int lcur[BUCK_SZ];
    __shared__ int lsc[BUCK_SZ];
    __shared__ int ptot;
    int b  = blockIdx.x;
    int lo = b * BUCK_SZ;
    int nn = N_NODES - lo; if (nn > BUCK_SZ) nn = BUCK_SZ;
    int e0 = b * CAP;
    int cnt = gcur[b] - e0; if (cnt > CAP) cnt = CAP;
    int t = threadIdx.x;
    if (t < BUCK_SZ) lcur[t] = 0;
    __syncthreads();
    for (int i = t; i < cnt; i += 512) atomicAdd(&lcur[pairs[e0 + i] >> 24], 1);
    __syncthreads();
    int deg = 0, pdeg = 0;
    if (t < BUCK_SZ) {
        deg  = lcur[t];
        pdeg = (deg + 15) & ~15;
        if (pdeg > 2032) pdeg = 2032;        // nch fits 7 bits (never expected)
        lsc[t] = pdeg;
    }
    __syncthreads();
    #pragma unroll
    for (int d = 1; d < BUCK_SZ; d <<= 1) {
        int add = 0;
        if (t < BUCK_SZ && t >= d) add = lsc[t - d];
        __syncthreads();
        if (t < BUCK_SZ) lsc[t] += add;
        __syncthreads();
    }
    if (t == BUCK_SZ - 1) ptot = lsc[t];
    if (t < BUCK_SZ) {
        int exc = lsc[t] - pdeg;
        if (t < nn) poff[lo + t] = (e0 + exc) | ((pdeg >> 4) << 24);
        lcur[t] = exc;
    }
    __syncthreads();
    int pt = ptot;
    if (pt <= CLUS_CAP) {
        for (int i = t; i < pt; i += 512) ladj[i] = N_NODES;
        __syncthreads();
        for (int i = t; i < cnt; i += 512) {
            unsigned p = pairs[e0 + i];
            int pos = atomicAdd(&lcur[p >> 24], 1);
            ladj[pos] = (int)(p & 0xFFFFFFu);
        }
        __syncthreads();
        for (int i = t; i < pt; i += 512) adj[e0 + i] = ladj[i];
    } else {                                  // safety fallback (never expected)
        for (int i = t; i < pt && i < CAP + 4096; i += 512) adj[e0 + i] = N_NODES;
        __syncthreads();
        for (int i = t; i < cnt; i += 512) {
            unsigned p = pairs[e0 + i];
            int pos = atomicAdd(&lcur[p >> 24], 1);
            if (pos < CAP + 4096) adj[e0 + pos] = (int)(p & 0xFFFFFFu);
        }
    }
}

// ---------------- Layer 1 (F_IN = 3): 16 lanes/node, quad output ------------

__global__ __launch_bounds__(512) void k_layer1(
        const float* __restrict__ x, const int* __restrict__ poff,
        const int* __restrict__ adj, const float* __restrict__ epsp,
        const float* __restrict__ W1, const float* __restrict__ b1,
        unsigned short* __restrict__ hout) {
    int tid  = blockIdx.x * 512 + threadIdx.x;
    int node = tid >> 4;
    if (node >= N_NODES) return;
    int sl = threadIdx.x & 15;
    int pk = poff[node];
    int st = pk & 0xFFFFFF;
    int nch = (unsigned)pk >> 24;
    float a0 = 0.f, a1 = 0.f, a2 = 0.f;
    for (int c = 0; c < nch; ++c) {
        int s = adj[st + (c << 4) + sl];
        bool ok = s < N_NODES;
        int sc = ok ? s : 0;
        float m = ok ? 1.f : 0.f;
        a0 += m * x[sc * 3 + 0];
        a1 += m * x[sc * 3 + 1];
        a2 += m * x[sc * 3 + 2];
    }
    #pragma unroll
    for (int d = 1; d < 16; d <<= 1) {       // reduce within the node's 16 lanes
        a0 += __shfl_xor(a0, d);
        a1 += __shfl_xor(a1, d);
        a2 += __shfl_xor(a2, d);
    }
    float ep = 1.0f + epsp[0];
    float s0 = ep * x[node * 3 + 0] + a0;
    float s1 = ep * x[node * 3 + 1] + a1;
    float s2 = ep * x[node * 3 + 2] + a2;
    float f[4];
    #pragma unroll
    for (int j = 0; j < 4; ++j) {
        int n = sl * 4 + j;
        f[j] = fmaxf(b1[n] + s0 * W1[n] + s1 * W1[64 + n] + s2 * W1[128 + n], 0.f);
    }
    uint2 o;
    o.x = (unsigned)f2bf(f[0]) | ((unsigned)f2bf(f[1]) << 16);
    o.y = (unsigned)f2bf(f[2]) | ((unsigned)f2bf(f[3]) << 16);
    ((uint2*)hout)[(size_t)node * 16 + sl] = o;
}

// ---------------- Dense GEMM: Y = h @ W  (100000x64 @ 64x64, bf16 MFMA) -------

__global__ __launch_bounds__(256) void k_gemm(
        const unsigned short* __restrict__ hin, const float* __restrict__ W,
        unsigned short* __restrict__ Y) {
    int lane = threadIdx.x & 63;
    int r = lane & 15;
    int g = lane >> 4;
    int wave   = blockIdx.x * (blockDim.x >> 6) + (threadIdx.x >> 6);
    int nwaves = gridDim.x * (blockDim.x >> 6);

    short8 bh[2][4], bl[2][4];
    #pragma unroll
    for (int s = 0; s < 2; ++s) {
        #pragma unroll
        for (int t = 0; t < 4; ++t) {
            short8 hv, lv;
            #pragma unroll
            for (int i = 0; i < 8; ++i) {
                int k = s * 32 + g * 8 + i;
                int n = t * 16 + r;
                float w = W[k * 64 + n];
                unsigned short wh = f2bf(w);
                float whf = bf2f(wh);
                hv[i] = (short)wh;
                lv[i] = (short)f2bf(w - whf);
            }
            bh[s][t] = hv; bl[s][t] = lv;
        }
    }

    const int NT = N_NODES / 16;   // 6250 (exact)
    for (int mt = wave; mt < NT; mt += nwaves) {
        const unsigned short* arow = hin + (size_t)(mt * 16 + r) * 64;
        short8 a0 = *(const short8*)(arow + g * 8);
        short8 a1 = *(const short8*)(arow + 32 + g * 8);
        #pragma unroll
        for (int t = 0; t < 4; ++t) {
            f32x4 acc = {0.f, 0.f, 0.f, 0.f};
            acc = __builtin_amdgcn_mfma_f32_16x16x32_bf16(a0, bh[0][t], acc, 0, 0, 0);
            acc = __builtin_amdgcn_mfma_f32_16x16x32_bf16(a0, bl[0][t], acc, 0, 0, 0);
            acc = __builtin_amdgcn_mfma_f32_16x16x32_bf16(a1, bh[1][t], acc, 0, 0, 0);
            acc = __builtin_amdgcn_mfma_f32_16x16x32_bf16(a1, bl[1][t], acc, 0, 0, 0);
            #pragma unroll
            for (int j = 0; j < 4; ++j) {
                sth(&Y[(size_t)(mt * 16 + g * 4 + j) * 64 + t * 16 + r], acc[j]);
            }
        }
    }
}

// ---------------- Gather: out = relu(b + (1+eps)*Y_self + sum_nbr Y_nbr) ------
// 16 lanes per node. Padded, mask-free: adj lists are multiples of 16 with
// sentinel N_NODES pointing at an all-zero row. dd[16] uint2 in flight.

__device__ inline void gather_node(
        const uint2* __restrict__ h2, int st, int nch,
        const int* __restrict__ adj, int sl, int g4,
        float& a0, float& a1, float& a2, float& a3) {
    for (int c = 0; c < nch; ++c) {
        int idxv = adj[st + (c << 4) + sl];
        uint2 dd[16];
        #pragma unroll
        for (int k = 0; k < 16; ++k) {
            int s = __shfl(idxv, (g4 << 4) + k);
            dd[k] = h2[(size_t)s * 16 + sl];
        }
        #pragma unroll
        for (int k = 0; k < 16; ++k) {
            a0 += bflo(dd[k].x); a1 += bfhi(dd[k].x);
            a2 += bflo(dd[k].y); a3 += bfhi(dd[k].y);
        }
    }
}

__global__ __launch_bounds__(512) void k_gather(
        const unsigned short* __restrict__ Y, const int* __restrict__ poff,
        const int* __restrict__ adj, const float* __restrict__ epsp,
        const float* __restrict__ b, unsigned short* __restrict__ hout) {
    int tid  = blockIdx.x * 512 + threadIdx.x;
    int node = tid >> 4;
    if (node >= N_NODES) return;
    int sl = threadIdx.x & 15;
    int g4 = (threadIdx.x >> 4) & 3;
    int pk = poff[node];
    int st = pk & 0xFFFFFF;
    int nch = (unsigned)pk >> 24;
    const uint2* h2 = (const uint2*)Y;
    float a0 = 0.f, a1 = 0.f, a2 = 0.f, a3 = 0.f;
    gather_node(h2, st, nch, adj, sl, g4, a0, a1, a2, a3);
    uint2 ds = h2[(size_t)node * 16 + sl];
    float ep = 1.0f + epsp[0];
    a0 = fmaxf(a0 + ep * bflo(ds.x) + b[4 * sl + 0], 0.f);
    a1 = fmaxf(a1 + ep * bfhi(ds.x) + b[4 * sl + 1], 0.f);
    a2 = fmaxf(a2 + ep * bflo(ds.y) + b[4 * sl + 2], 0.f);
    a3 = fmaxf(a3 + ep * bfhi(ds.y) + b[4 * sl + 3], 0.f);
    uint2 o;
    o.x = (unsigned int)f2bf(a0) | ((unsigned int)f2bf(a1) << 16);
    o.y = (unsigned int)f2bf(a2) | ((unsigned int)f2bf(a3) << 16);
    ((uint2*)hout)[(size_t)node * 16 + sl] = o;
}

__global__ __launch_bounds__(512) void k_gather_pool(
        const unsigned short* __restrict__ Y, const int* __restrict__ poff,
        const int* __restrict__ adj, const float* __restrict__ epsp,
        const float* __restrict__ b, const int* __restrict__ batch,
        float* __restrict__ pooled, int* __restrict__ cnt) {
    __shared__ float sacc[8 * 64];
    __shared__ int   scnt[8];
    for (int i = threadIdx.x; i < 8 * 64; i += 512) sacc[i] = 0.f;
    if (threadIdx.x < 8) scnt[threadIdx.x] = 0;
    __syncthreads();

    int tid  = blockIdx.x * 512 + threadIdx.x;
    int node = tid >> 4;
    int sl = threadIdx.x & 15;
    int g4 = (threadIdx.x >> 4) & 3;
    int g0 = clampi(batch[clampi(blockIdx.x * 32, 0, N_NODES - 1)], 0, N_GRAPHS - 1);

    if (node < N_NODES) {
        int pk = poff[node];
        int st = pk & 0xFFFFFF;
        int nch = (unsigned)pk >> 24;
        const uint2* h2 = (const uint2*)Y;
        float a0 = 0.f, a1 = 0.f, a2 = 0.f, a3 = 0.f;
        gather_node(h2, st, nch, adj, sl, g4, a0, a1, a2, a3);
        uint2 ds = h2[(size_t)node * 16 + sl];
        float ep = 1.0f + epsp[0];
        a0 = fmaxf(a0 + ep * bflo(ds.x) + b[4 * sl + 0], 0.f);
        a1 = fmaxf(a1 + ep * bfhi(ds.x) + b[4 * sl + 1], 0.f);
        a2 = fmaxf(a2 + ep * bflo(ds.y) + b[4 * sl + 2], 0.f);
        a3 = fmaxf(a3 + ep * bfhi(ds.y) + b[4 * sl + 3], 0.f);
        int g  = clampi(batch[node], 0, N_GRAPHS - 1);
        int og = g - g0;
        if (og >= 0 && og < 8) {
            atomicAdd(&sacc[og * 64 + 4 * sl + 0], a0);
            atomicAdd(&sacc[og * 64 + 4 * sl + 1], a1);
            atomicAdd(&sacc[og * 64 + 4 * sl + 2], a2);
            atomicAdd(&sacc[og * 64 + 4 * sl + 3], a3);
            if (sl == 0) atomicAdd(&scnt[og], 1);
        } else {
            atomicAdd(&pooled[g * 64 + 4 * sl + 0], a0);
            atomicAdd(&pooled[g * 64 + 4 * sl + 1], a1);
            atomicAdd(&pooled[g * 64 + 4 * sl + 2], a2);
            atomicAdd(&pooled[g * 64 + 4 * sl + 3], a3);
            if (sl == 0) atomicAdd(&cnt[g], 1);
        }
    }
    __syncthreads();
    int w = threadIdx.x >> 6;                // waves 0..7 flush slots
    int lane = threadIdx.x & 63;
    if (w < 8) {
        int c = scnt[w];
        if (c > 0) {
            atomicAdd(&pooled[(g0 + w) * 64 + lane], sacc[w * 64 + lane]);
            if (lane == 0) atomicAdd(&cnt[g0 + w], c);
        }
    }
}

// ---------------- Head: mean, 64->10 relu, 10->1 ----------------

__global__ __launch_bounds__(256) void k_head(
        const float* __restrict__ pooled, const int* __restrict__ cnt,
        const float* __restrict__ Wf1, const float* __restrict__ bf1,
        const float* __restrict__ Wf2, const float* __restrict__ bf2,
        float* __restrict__ out) {
    int g = blockIdx.x * blockDim.x + threadIdx.x;
    if (g >= N_GRAPHS) return;
    float inv = 1.0f / fmaxf((float)cnt[g], 1.0f);
    float p[64];
    #pragma unroll
    for (int k = 0; k < 64; ++k) p[k] = pooled[g * 64 + k] * inv;
    float o = bf2[0];
    #pragma unroll
    for (int j = 0; j < 10; ++j) {
        float s = bf1[j];
        #pragma unroll
        for (int k = 0; k < 64; ++k) s += p[k] * Wf1[k * 10 + j];
        o += fmaxf(s, 0.f) * Wf2[j];
    }
    out[g] = o;
}

// ---------------- launch ----------------

extern "C" void kernel_launch(void* const* d_in, const int* in_sizes, int n_in,
                              void* d_out, int out_size, void* d_ws, size_t ws_size,
                              hipStream_t stream) {
    const float* x     = (const float*)d_in[0];
    const int*   ei    = (const int*)d_in[1];    // int64 in ref -> int32 on device
    const int*   batch = (const int*)d_in[2];
    const float* eps1 = (const float*)d_in[3];
    const float* eps2 = (const float*)d_in[4];
    const float* eps3 = (const float*)d_in[5];
    const float* W1 = (const float*)d_in[6];
    const float* b1 = (const float*)d_in[7];
    const float* W2 = (const float*)d_in[8];
    const float* b2 = (const float*)d_in[9];
    const float* W3 = (const float*)d_in[10];
    const float* b3 = (const float*)d_in[11];
    const float* Wf1 = (const float*)d_in[12];
    const float* bf1 = (const float*)d_in[13];
    const float* Wf2 = (const float*)d_in[14];
    const float* bf2 = (const float*)d_in[15];
    float* out = (float*)d_out;

    const size_t HROWS = (size_t)(N_NODES + 1) * HDIM;   // +1 sentinel zero row

    char* base = (char*)d_ws;
    unsigned short* hA = (unsigned short*)base;                 // 12.800128 MB
    unsigned short* hB = (unsigned short*)(base + HROWS * 2);   // 12.800128 MB
    unsigned* pairs = (unsigned*)base;   // 25.6 MB, aliases hA+hB (build only)
    char* q = base + 2 * HROWS * 2;
    float* pooled = (float*)q;            q += 64000ull * 4;
    int*   cnt    = (int*)q;              q += 1000ull * 4;
    int*   poff   = (int*)q;              q += 100000ull * 4;
    int*   gcur   = (int*)q;              q += 512ull * 4;
    int*   adj    = (int*)q;              // NBUCK*CAP + 4096 ints

    const int TB = 256;
    // CSR build: init cursors -> bin (packed pairs, slack buckets) -> cluster
    k_curinit<<<(NBUCK + TB - 1) / TB, TB, 0, stream>>>(gcur);
    const int BINB = (N_EDGES + BIN_CHUNK - 1) / BIN_CHUNK;   // 782
    k_bin<<<BINB, BIN_T, 0, stream>>>(ei, gcur, pairs);
    k_cluster<<<NBUCK, 512, 0, stream>>>(pairs, gcur, poff, adj);

    // pooled/cnt zero + sentinel rows (after pairs region is dead)
    k_zero<<<(65000 + TB - 1) / TB, TB, 0, stream>>>((int*)pooled, 65000);
    k_zrow<<<1, 64, 0, stream>>>((uint2*)hA, (uint2*)hB);

    const int GB = (N_NODES * 16 + 511) / 512;               // 3125 (32 nodes/blk)

    // layer 1 (16 lanes/node, quad output)
    k_layer1<<<GB, 512, 0, stream>>>(x, poff, adj, eps1, W1, b1, hA);
    // layer 2: GEMM then gather
    k_gemm<<<256, 256, 0, stream>>>(hA, W2, hB);
    k_gather<<<GB, 512, 0, stream>>>(hB, poff, adj, eps2, b2, hA);
    // layer 3: GEMM then gather+pool
    k_gemm<<<256, 256, 0, stream>>>(hA, W3, hB);
    k_gather_pool<<<GB, 512, 0, stream>>>(hB, poff, adj, eps3, b3, batch, pooled, cnt);

    k_head<<<(N_GRAPHS + TB - 1) / TB, TB, 0, stream>>>(pooled, cnt, Wf1, bf1, Wf2, bf2, out);
}